// Round 1
// baseline (1182.830 us; speedup 1.0000x reference)
//
#include <hip/hip_runtime.h>
#include <stdint.h>

#define NROWS 8192
#define KDIM  64
#define NCOLS 32000

typedef __attribute__((ext_vector_type(8))) short short8;
typedef __attribute__((ext_vector_type(8))) unsigned short ushort8;
typedef __attribute__((ext_vector_type(4))) float floatx4;

__device__ __forceinline__ unsigned short f2bf(float f) {
    unsigned int u = __float_as_uint(f);
    u += 0x7fffu + ((u >> 16) & 1u);   // round-to-nearest-even
    return (unsigned short)(u >> 16);
}

// ---------------------------------------------------------------------------
// prep: Wt[n][k] = bf16(W[k][n]) (transposed so B-fragments are contiguous),
//       Abf[m][k] = bf16(1/x[m][k]), aux = 0.
// grid: 500 W-blocks + 64 A-blocks + 1 aux block, 256 threads each.
// ---------------------------------------------------------------------------
__global__ __launch_bounds__(256) void prep_kernel(
        const float* __restrict__ x, const float* __restrict__ W,
        unsigned short* __restrict__ Wt, unsigned short* __restrict__ Abf,
        float* __restrict__ aux_ptr) {
    int b = blockIdx.x, t = threadIdx.x;
    if (b < 500) {
        __shared__ unsigned short lds[64 * 72];   // 64 n-rows x 64 k, padded
        int n0 = b * 64;
        #pragma unroll
        for (int i = 0; i < 16; ++i) {
            int flat = i * 256 + t;       // 0..4095
            int k = flat >> 6;            // 0..63
            int n = flat & 63;            // coalesced in n
            lds[n * 72 + k] = f2bf(W[k * NCOLS + n0 + n]);
        }
        __syncthreads();
        #pragma unroll
        for (int i = 0; i < 2; ++i) {
            int c = i * 256 + t;          // 512 chunks of 8 ushorts
            int n = c >> 3;
            int off = (c & 7) * 8;
            ushort8 v = *(const ushort8*)&lds[n * 72 + off];
            *(ushort8*)&Wt[(n0 + n) * 64 + off] = v;   // coalesced 16B stores
        }
    } else if (b < 564) {
        int idx0 = (b - 500) * 256 + t;   // 16384 threads, 32 iters = 524288
        #pragma unroll
        for (int i = 0; i < 32; ++i) {
            int idx = idx0 + i * 16384;
            Abf[idx] = f2bf(1.0f / x[idx]);
        }
    } else if (t == 0) {
        *aux_ptr = 0.0f;                  // aux_loss is exactly 0
    }
}

// ---------------------------------------------------------------------------
// rowsum: Spart[split][row] = sum over this split's cols of exp(logit).
// grid (128 row-tiles, 4 col-splits), 256 threads (4 waves).
// Each block: 64 rows, 8000 cols; wave w covers cols {base + w*16 + 64t}.
// Deterministic (no atomics).
// ---------------------------------------------------------------------------
__global__ __launch_bounds__(256) void rowsum_kernel(
        const unsigned short* __restrict__ Abf,
        const unsigned short* __restrict__ Wt,
        float* __restrict__ Spart) {
    int bx = blockIdx.x;          // row tile
    int split = blockIdx.y;       // col split
    int t = threadIdx.x;
    int w = t >> 6, lane = t & 63, l15 = lane & 15, q = lane >> 4;
    int row0 = bx * 64;

    // A fragments: A[m=l15][k=q*8+j], two K-halves, 4 m-tiles
    short8 a[4][2];
    #pragma unroll
    for (int mt = 0; mt < 4; ++mt)
        #pragma unroll
        for (int kh = 0; kh < 2; ++kh)
            a[mt][kh] = *(const short8*)(Abf + (row0 + mt * 16 + l15) * 64 + kh * 32 + q * 8);

    float sums[4][4];
    #pragma unroll
    for (int mt = 0; mt < 4; ++mt)
        #pragma unroll
        for (int r = 0; r < 4; ++r) sums[mt][r] = 0.0f;

    int colbase = split * 8000 + w * 16 + l15;
    for (int it = 0; it < 125; ++it) {
        int n = colbase + it * 64;
        const unsigned short* wp = Wt + n * 64 + q * 8;
        short8 b0 = *(const short8*)(wp);        // B[k=q*8+j][n=l15]
        short8 b1 = *(const short8*)(wp + 32);   // second K-half
        #pragma unroll
        for (int mt = 0; mt < 4; ++mt) {
            floatx4 c = {0.0f, 0.0f, 0.0f, 0.0f};
            c = __builtin_amdgcn_mfma_f32_16x16x32_bf16(a[mt][0], b0, c, 0, 0, 0);
            c = __builtin_amdgcn_mfma_f32_16x16x32_bf16(a[mt][1], b1, c, 0, 0, 0);
            #pragma unroll
            for (int r = 0; r < 4; ++r) sums[mt][r] += __expf(c[r]);
        }
    }

    // reduce the 16 lanes (same q, varying l15) that share a row
    __shared__ float red[4][64];
    #pragma unroll
    for (int mt = 0; mt < 4; ++mt)
        #pragma unroll
        for (int r = 0; r < 4; ++r) {
            float s = sums[mt][r];
            s += __shfl_xor(s, 1);
            s += __shfl_xor(s, 2);
            s += __shfl_xor(s, 4);
            s += __shfl_xor(s, 8);
            if (l15 == 0) red[w][mt * 16 + q * 4 + r] = s;
        }
    __syncthreads();
    if (t < 64)
        Spart[split * NROWS + row0 + t] =
            red[0][t] + red[1][t] + red[2][t] + red[3][t];
}

// ---------------------------------------------------------------------------
// out: out[m][n] = exp(logit) / S[m]. grid (250 col-tiles, 256 row-tiles),
// block tile 32 rows x 128 cols, 256 threads (4 waves, wave w -> cols w*32..).
// LDS-staged so stores are coalesced float4.
// ---------------------------------------------------------------------------
__global__ __launch_bounds__(256) void out_kernel(
        const unsigned short* __restrict__ Abf,
        const unsigned short* __restrict__ Wt,
        const float* __restrict__ Spart,
        float* __restrict__ out) {
    int bx = blockIdx.x;          // col tile (0..249)
    int by = blockIdx.y;          // row tile (0..255)
    int t = threadIdx.x;
    int w = t >> 6, lane = t & 63, l15 = lane & 15, q = lane >> 4;
    int row0 = by * 32, n0 = bx * 128;

    __shared__ float rinv_s[32];
    __shared__ float tile[32 * 128];

    if (t < 32) {
        int row = row0 + t;
        float S = Spart[row] + Spart[NROWS + row] +
                  Spart[2 * NROWS + row] + Spart[3 * NROWS + row];
        rinv_s[t] = 1.0f / S;
    }

    short8 a[2][2];
    #pragma unroll
    for (int mt = 0; mt < 2; ++mt)
        #pragma unroll
        for (int kh = 0; kh < 2; ++kh)
            a[mt][kh] = *(const short8*)(Abf + (row0 + mt * 16 + l15) * 64 + kh * 32 + q * 8);

    __syncthreads();   // rinv_s ready

    #pragma unroll
    for (int ng = 0; ng < 2; ++ng) {
        int n = n0 + w * 32 + ng * 16 + l15;
        const unsigned short* wp = Wt + n * 64 + q * 8;
        short8 b0 = *(const short8*)(wp);
        short8 b1 = *(const short8*)(wp + 32);
        #pragma unroll
        for (int mt = 0; mt < 2; ++mt) {
            floatx4 c = {0.0f, 0.0f, 0.0f, 0.0f};
            c = __builtin_amdgcn_mfma_f32_16x16x32_bf16(a[mt][0], b0, c, 0, 0, 0);
            c = __builtin_amdgcn_mfma_f32_16x16x32_bf16(a[mt][1], b1, c, 0, 0, 0);
            #pragma unroll
            for (int r = 0; r < 4; ++r) {
                int rl = mt * 16 + q * 4 + r;    // block-local row
                tile[rl * 128 + w * 32 + ng * 16 + l15] = __expf(c[r]) * rinv_s[rl];
            }
        }
    }
    __syncthreads();

    // coalesced float4 stores: 32 rows x 128 cols = 1024 float4, 4 per thread
    #pragma unroll
    for (int i = 0; i < 4; ++i) {
        int flat = i * 256 + t;
        int rl = flat >> 5;          // row (32 float4 per row)
        int cf = flat & 31;
        floatx4 v = *(const floatx4*)&tile[rl * 128 + cf * 4];
        *(floatx4*)(out + (size_t)(row0 + rl) * NCOLS + n0 + cf * 4) = v;
    }
}

extern "C" void kernel_launch(void* const* d_in, const int* in_sizes, int n_in,
                              void* d_out, int out_size, void* d_ws, size_t ws_size,
                              hipStream_t stream) {
    const float* x = (const float*)d_in[0];             // (8192, 64)
    const float* W = (const float*)d_in[1];             // (64, 32000)
    // d_in[2] (sparsity_weights) only feeds aux_loss, which is exactly 0.
    float* out = (float*)d_out;

    unsigned short* Wt  = (unsigned short*)d_ws;                    // 64*32000 bf16 = 4,096,000 B
    unsigned short* Abf = Wt + (size_t)KDIM * NCOLS;                // 8192*64 bf16 = 1,048,576 B
    float* Spart = (float*)(Abf + (size_t)NROWS * KDIM);            // 4*8192 fp32 = 131,072 B
    float* aux = out + ((size_t)out_size - 1);

    prep_kernel<<<565, 256, 0, stream>>>(x, W, Wt, Abf, aux);
    rowsum_kernel<<<dim3(128, 4), 256, 0, stream>>>(Abf, Wt, Spart);
    out_kernel<<<dim3(250, 256), 256, 0, stream>>>(Abf, Wt, Spart, out);
}